// Round 10
// baseline (295.831 us; speedup 1.0000x reference)
//
#include <hip/hip_runtime.h>
#include <hip/hip_bf16.h>

#define B_   1024
#define N_   128
#define H_   128
#define FE_  8
#define G3_  384       // 3*H

typedef short s8v __attribute__((ext_vector_type(8)));   // 8 bf16 (4 VGPRs)
typedef float f4v __attribute__((ext_vector_type(4)));   // 4 fp32 accum

static __device__ __forceinline__ unsigned short f2bf(float x) {  // RNE
    unsigned int u = __float_as_uint(x);
    u += 0x7fffu + ((u >> 16) & 1u);
    return (unsigned short)(u >> 16);
}
static __device__ __forceinline__ float bf2f(unsigned short s) {
    return __uint_as_float(((unsigned int)s) << 16);
}

// ---------------------------------------------------------------------------
// k0: split W_hh (49152) and W_ih[:,128:136] (3072) into bf16 hi/lo planes.
// Grid 204*256 = 52224 = exact element count.
// ---------------------------------------------------------------------------
__global__ __launch_bounds__(256) void k0_split(
    const float* __restrict__ W_hh, const float* __restrict__ W_ih,
    unsigned short* __restrict__ Whi, unsigned short* __restrict__ Wlo,
    unsigned short* __restrict__ Wth, unsigned short* __restrict__ Wtl)
{
    const int i = blockIdx.x * 256 + threadIdx.x;
    if (i < 49152) {
        const float x = W_hh[i];
        const unsigned short hb = f2bf(x);
        Whi[i] = hb;
        Wlo[i] = f2bf(x - bf2f(hb));
    } else {
        const int j = i - 49152;               // 0..3071
        const float x = W_ih[(j >> 3) * 136 + 128 + (j & 7)];
        const unsigned short hb = f2bf(x);
        Wth[j] = hb;
        Wtl[j] = f2bf(x - bf2f(hb));
    }
}

// ---------------------------------------------------------------------------
// Fused per-jet kernel: 1 block = 1 jet (128 particles), 512 threads / 8 waves.
//   P1 stage: h[b] -> hi/lo bf16 LDS planes (swizzled 16B slots, r8-verified)
//   P2 hsum: column sum over LDS planes (hi+lo = h to 2^-25 rel)
//   P3 message: wave-coalesced GEMV rows of Wm + shfl_xor butterfly, tanh
//   P4 gi:      same over 384 rows of W_ih[:, :128] + b_ih
//   P5 GEMM + GRU epilogue: verbatim round-8 MFMA structure, rp = 0..3,
//      epilogue h reconstructed from LDS planes (no 3rd HBM read of h).
// HW-verified MFMA layouts (r7/r8 passed): A lane=row(l&15),k=(l>>4)*8+e;
// B lane=col,k likewise; D col=l&15,row=(l>>4)*4+reg.
// ---------------------------------------------------------------------------
__global__ __launch_bounds__(512, 4) void k_fused(
    const float* __restrict__ h, const float* __restrict__ jets,
    const float* __restrict__ Wm, const float* __restrict__ bm,
    const float* __restrict__ W_ih, const float* __restrict__ b_ih,
    const unsigned short* __restrict__ Whi, const unsigned short* __restrict__ Wlo,
    const unsigned short* __restrict__ Wth, const unsigned short* __restrict__ Wtl,
    const float* __restrict__ b_hh, float* __restrict__ out)
{
    __shared__ __align__(16) unsigned short Ah[N_ * H_];   // 32 KB hi plane
    __shared__ __align__(16) unsigned short Al[N_ * H_];   // 32 KB lo plane
    __shared__ __align__(16) float red[512];               // colsum scratch
    __shared__ __align__(16) float hsum_s[H_];
    __shared__ __align__(16) float msg_s[H_];
    __shared__ __align__(16) float gi_s[G3_];

    const int t    = threadIdx.x;
    const int b    = blockIdx.x;
    const int row0 = b * N_;             // global particle row base
    const int wv   = t >> 6;             // wave 0..7
    const int l    = t & 63;
    const int lr   = l & 15;
    const int lq   = l >> 4;
    const int col  = wv * 16 + lr;       // output column owned by this lane

    // ---- P1: stage h -> hi/lo planes (2 rows per thread, r8 pattern) ----
    {
        const int rb = t >> 3;                  // 0..63
        const int kq = (t & 7) * 16;            // float col start
        #pragma unroll
        for (int half = 0; half < 2; ++half) {
            const int r = rb + half * 64;
            const float4* src = reinterpret_cast<const float4*>(
                h + (size_t)(row0 + r) * H_ + kq);
            float xs[16];
            #pragma unroll
            for (int i = 0; i < 4; ++i) {
                const float4 v = src[i];
                xs[i*4+0] = v.x; xs[i*4+1] = v.y; xs[i*4+2] = v.z; xs[i*4+3] = v.w;
            }
            #pragma unroll
            for (int c = 0; c < 2; ++c) {
                s8v hv8, lv8;
                #pragma unroll
                for (int e = 0; e < 8; ++e) {
                    const float x = xs[c * 8 + e];
                    const unsigned short hb = f2bf(x);
                    hv8[e] = (short)hb;
                    lv8[e] = (short)f2bf(x - bf2f(hb));
                }
                const int s = ((kq >> 3) + c) ^ (r & 7);   // swizzled 16B slot
                *reinterpret_cast<s8v*>(&Ah[r * H_ + s * 8]) = hv8;
                *reinterpret_cast<s8v*>(&Al[r * H_ + s * 8]) = lv8;
            }
        }
    }
    __syncthreads();

    // ---- P2: hsum[c] = sum_r h[r,c] (from planes) ----
    {
        const int c = t & 127, q = t >> 7;      // q = row quarter 0..3
        float a = 0.f;
        #pragma unroll 8
        for (int i = 0; i < 32; ++i) {
            const int r   = q * 32 + i;
            const int idx = r * H_ + ((((c >> 3) ^ (r & 7)) << 3) + (c & 7));
            a += bf2f(Ah[idx]) + bf2f(Al[idx]);
        }
        red[q * 128 + c] = a;
    }
    __syncthreads();
    if (t < 128) hsum_s[t] = red[t] + red[128 + t] + red[256 + t] + red[384 + t];
    __syncthreads();

    // ---- P3: message = tanh(hsum.Wm^T + N*bm), coalesced wave-GEMV ----
    {
        const float2 hs2 = make_float2(hsum_s[2 * l], hsum_s[2 * l + 1]);
        for (int i = 0; i < 16; ++i) {
            const int g = wv * 16 + i;
            const float2 w = *reinterpret_cast<const float2*>(Wm + g * H_ + 2 * l);
            float d = hs2.x * w.x + hs2.y * w.y;
            d += __shfl_xor(d, 1);  d += __shfl_xor(d, 2);
            d += __shfl_xor(d, 4);  d += __shfl_xor(d, 8);
            d += __shfl_xor(d, 16); d += __shfl_xor(d, 32);
            if (l == 0) msg_s[g] = tanhf(d + (float)N_ * bm[g]);
        }
    }
    __syncthreads();

    // ---- P4: gi[g] = msg.W_ih[g,:128] + b_ih[g] ----
    {
        const float2 ms2 = make_float2(msg_s[2 * l], msg_s[2 * l + 1]);
        for (int i = 0; i < 48; ++i) {
            const int g = wv * 48 + i;
            const float2 w = *reinterpret_cast<const float2*>(W_ih + g * 136 + 2 * l);
            float d = ms2.x * w.x + ms2.y * w.y;
            d += __shfl_xor(d, 1);  d += __shfl_xor(d, 2);
            d += __shfl_xor(d, 4);  d += __shfl_xor(d, 8);
            d += __shfl_xor(d, 16); d += __shfl_xor(d, 32);
            if (l == 0) gi_s[g] = d + b_ih[g];
        }
    }
    __syncthreads();

    // ---- P5: GEMM (split-bf16 MFMA) + GRU epilogue ----
    float gb[3], bh3[3];
    #pragma unroll
    for (int g = 0; g < 3; ++g) {
        gb[g]  = gi_s[(g << 7) + col];
        bh3[g] = b_hh[(g << 7) + col];
    }

    #pragma unroll
    for (int rp = 0; rp < 4; ++rp) {            // rows rp*32 .. rp*32+31
        f4v acc[2][3];                           // [rt][gate]
        f4v accT[2];                             // n-gate jets-tail
        #pragma unroll
        for (int rt = 0; rt < 2; ++rt) {
            #pragma unroll
            for (int g = 0; g < 3; ++g)
                #pragma unroll
                for (int e = 0; e < 4; ++e) acc[rt][g][e] = 0.f;
            #pragma unroll
            for (int e = 0; e < 4; ++e) accT[rt][e] = 0.f;
        }

        #pragma unroll
        for (int ks = 0; ks < 4; ++ks) {
            s8v aH[2], aL[2];
            #pragma unroll
            for (int rt = 0; rt < 2; ++rt) {
                const int r   = rp * 32 + rt * 16 + lr;
                const int idx = r * H_ + ((((ks << 2) + lq) ^ (r & 7)) << 3);
                aH[rt] = *reinterpret_cast<const s8v*>(&Ah[idx]);
                aL[rt] = *reinterpret_cast<const s8v*>(&Al[idx]);
            }
            #pragma unroll
            for (int g = 0; g < 3; ++g) {
                const int off = ((g << 7) + col) * H_ + ks * 32 + lq * 8;
                const s8v bH = *reinterpret_cast<const s8v*>(Whi + off);
                const s8v bL = *reinterpret_cast<const s8v*>(Wlo + off);
                #pragma unroll
                for (int rt = 0; rt < 2; ++rt) {
                    acc[rt][g] = __builtin_amdgcn_mfma_f32_16x16x32_bf16(
                        aH[rt], bH, acc[rt][g], 0, 0, 0);
                    acc[rt][g] = __builtin_amdgcn_mfma_f32_16x16x32_bf16(
                        aH[rt], bL, acc[rt][g], 0, 0, 0);
                    acc[rt][g] = __builtin_amdgcn_mfma_f32_16x16x32_bf16(
                        aL[rt], bH, acc[rt][g], 0, 0, 0);
                }
            }
        }

        // jets tail (K 128..135): A nonzero only in lanes lq==0
        s8v aTh[2], aTl[2];
        #pragma unroll
        for (int rt = 0; rt < 2; ++rt) {
            const int row = row0 + rp * 32 + rt * 16 + lr;
            const float4 j0 = *reinterpret_cast<const float4*>(jets + (size_t)row * FE_);
            const float4 j1 = *reinterpret_cast<const float4*>(jets + (size_t)row * FE_ + 4);
            const float jx[8] = {j0.x, j0.y, j0.z, j0.w, j1.x, j1.y, j1.z, j1.w};
            #pragma unroll
            for (int e = 0; e < 8; ++e) {
                const float x = (lq == 0) ? jx[e] : 0.f;
                const unsigned short hb = f2bf(x);
                aTh[rt][e] = (short)hb;
                aTl[rt][e] = (short)f2bf(x - bf2f(hb));
            }
        }
        #pragma unroll
        for (int g = 0; g < 3; ++g) {
            const int gi = (g << 7) + col;
            const s8v bTh = *reinterpret_cast<const s8v*>(Wth + gi * 8);
            const s8v bTl = *reinterpret_cast<const s8v*>(Wtl + gi * 8);
            #pragma unroll
            for (int rt = 0; rt < 2; ++rt) {
                if (g < 2) {
                    acc[rt][g] = __builtin_amdgcn_mfma_f32_16x16x32_bf16(
                        aTh[rt], bTh, acc[rt][g], 0, 0, 0);
                    acc[rt][g] = __builtin_amdgcn_mfma_f32_16x16x32_bf16(
                        aTh[rt], bTl, acc[rt][g], 0, 0, 0);
                    acc[rt][g] = __builtin_amdgcn_mfma_f32_16x16x32_bf16(
                        aTl[rt], bTh, acc[rt][g], 0, 0, 0);
                } else {
                    accT[rt] = __builtin_amdgcn_mfma_f32_16x16x32_bf16(
                        aTh[rt], bTh, accT[rt], 0, 0, 0);
                    accT[rt] = __builtin_amdgcn_mfma_f32_16x16x32_bf16(
                        aTh[rt], bTl, accT[rt], 0, 0, 0);
                    accT[rt] = __builtin_amdgcn_mfma_f32_16x16x32_bf16(
                        aTl[rt], bTh, accT[rt], 0, 0, 0);
                }
            }
        }

        // GRU epilogue; h reconstructed from LDS planes (err ~2^-25 rel)
        #pragma unroll
        for (int rt = 0; rt < 2; ++rt) {
            #pragma unroll
            for (int ridx = 0; ridx < 4; ++ridx) {
                const int rl = rp * 32 + rt * 16 + lq * 4 + ridx;   // D-row
                const float rr = 1.f / (1.f + __expf(-(gb[0] + bh3[0] + acc[rt][0][ridx])));
                const float zz = 1.f / (1.f + __expf(-(gb[1] + bh3[1] + acc[rt][1][ridx])));
                const float i_n = gb[2] + accT[rt][ridx];
                const float h_n = acc[rt][2][ridx] + bh3[2];
                const float e2  = __expf(2.f * (i_n + rr * h_n));
                const float nn  = 1.f - 2.f / (e2 + 1.f);            // tanh
                const int hidx  = rl * H_ + ((((col >> 3) ^ (rl & 7)) << 3) + (col & 7));
                const float hv  = bf2f(Ah[hidx]) + bf2f(Al[hidx]);
                out[(size_t)(row0 + rl) * H_ + col] = (1.f - zz) * nn + zz * hv;
            }
        }
    }
}

// ---------------------------------------------------------------------------
extern "C" void kernel_launch(void* const* d_in, const int* in_sizes, int n_in,
                              void* d_out, int out_size, void* d_ws, size_t ws_size,
                              hipStream_t stream) {
    const float* h    = (const float*)d_in[0];
    const float* jets = (const float*)d_in[1];
    // d_in[2] = mask: unused by the reference forward
    const float* Wm   = (const float*)d_in[3];
    const float* bm   = (const float*)d_in[4];
    const float* W_ih = (const float*)d_in[5];
    const float* W_hh = (const float*)d_in[6];
    const float* b_ih = (const float*)d_in[7];
    const float* b_hh = (const float*)d_in[8];
    float* out = (float*)d_out;

    // d_ws layout (~204 KB, rewritten every call; all 16B-aligned)
    unsigned short* Whi = (unsigned short*)d_ws;                      // 98304 B
    unsigned short* Wlo = (unsigned short*)((char*)d_ws + 98304);     // 98304 B
    unsigned short* Wth = (unsigned short*)((char*)d_ws + 196608);    //  6144 B
    unsigned short* Wtl = (unsigned short*)((char*)d_ws + 202752);    //  6144 B

    k0_split<<<dim3(204), dim3(256), 0, stream>>>(W_hh, W_ih, Whi, Wlo, Wth, Wtl);
    k_fused<<<dim3(B_), dim3(512), 0, stream>>>(h, jets, Wm, bm, W_ih, b_ih,
                                                Whi, Wlo, Wth, Wtl, b_hh, out);
}